// Round 17
// baseline (335.973 us; speedup 1.0000x reference)
//
#include <hip/hip_runtime.h>
#include <cstdint>
#include <cstddef>

#define TDIM 4096       // B*S tokens
#define DDIM 1024
#define HDIM 4096
#define EDIM 8
#define CAPD 2048
#define NSLOT 8192      // T*K
#define NROUTERBLK 1024

typedef _Float16 f16;
typedef _Float16 f16x2 __attribute__((ext_vector_type(2)));
typedef _Float16 f16x4 __attribute__((ext_vector_type(4)));
typedef _Float16 f16x8 __attribute__((ext_vector_type(8)));
typedef float f32x4 __attribute__((ext_vector_type(4)));

__device__ __forceinline__ void gload16(const void* g, void* l) {
  __builtin_amdgcn_global_load_lds(
      (const __attribute__((address_space(1))) unsigned int*)g,
      (__attribute__((address_space(3))) unsigned int*)l, 16, 0, 0);
}

__device__ __forceinline__ float gelu_fast(float x) {
  float y = 1.5957691216057308f * (x + 0.044715f * x * x * x);
  y = fminf(y, 60.f);
  float e = __expf(y);
  return x * e * __builtin_amdgcn_rcpf(e + 1.f);
}

// ---------------- transpose + f32->f16 convert: src (E,R,C) -> dst (E,C,R) ----------------
__global__ __launch_bounds__(256)
void transpose_cvt(const float* __restrict__ src, f16* __restrict__ dst, int R, int C) {
  __shared__ float tile[64][65];
  const int e = blockIdx.z;
  const int c0 = blockIdx.x * 64, r0 = blockIdx.y * 64;
  const int tid = threadIdx.x;
  const float* s = src + (size_t)e * R * C;
  f16* d = dst + (size_t)e * R * C;
  #pragma unroll
  for (int p = 0; p < 4; ++p) {
    const int row = p * 16 + (tid >> 4);
    const int col = (tid & 15) * 4;
    float4 v = *(const float4*)(s + (size_t)(r0 + row) * C + c0 + col);
    tile[row][col] = v.x; tile[row][col + 1] = v.y;
    tile[row][col + 2] = v.z; tile[row][col + 3] = v.w;
  }
  __syncthreads();
  #pragma unroll
  for (int p = 0; p < 4; ++p) {
    const int crow = p * 16 + (tid >> 4);
    const int q = (tid & 15) * 4;
    f16x4 o;
    #pragma unroll
    for (int j = 0; j < 4; ++j) o[j] = (f16)tile[q + j][crow];
    *(f16x4*)(d + (size_t)(c0 + crow) * R + r0 + q) = o;
  }
}

// ---------------- router ----------------
__global__ void router_k(const float* __restrict__ x, const float* __restrict__ rw,
                         int* __restrict__ eidx, float* __restrict__ gates,
                         float* __restrict__ bps) {
  __shared__ float lrw[EDIM * DDIM];
  __shared__ float wps[4][EDIM];
  const int tid = threadIdx.x, lane = tid & 63, wv = tid >> 6;
  for (int i = tid; i < EDIM * DDIM; i += 256) lrw[i] = rw[i];
  __syncthreads();
  const int t = blockIdx.x * 4 + wv;
  float acc[EDIM];
  #pragma unroll
  for (int e = 0; e < EDIM; ++e) acc[e] = 0.f;
  const float* xr = x + (size_t)t * DDIM;
  #pragma unroll
  for (int j = 0; j < DDIM / 64; ++j) {
    float xv = xr[j * 64 + lane];
    #pragma unroll
    for (int e = 0; e < EDIM; ++e) acc[e] += xv * lrw[e * DDIM + j * 64 + lane];
  }
  #pragma unroll
  for (int off = 32; off >= 1; off >>= 1) {
    #pragma unroll
    for (int e = 0; e < EDIM; ++e) acc[e] += __shfl_xor(acc[e], off);
  }
  float mx = acc[0];
  #pragma unroll
  for (int e = 1; e < EDIM; ++e) mx = fmaxf(mx, acc[e]);
  float p[EDIM], s = 0.f;
  #pragma unroll
  for (int e = 0; e < EDIM; ++e) { p[e] = expf(acc[e] - mx); s += p[e]; }
  float inv = 1.f / s;
  #pragma unroll
  for (int e = 0; e < EDIM; ++e) p[e] *= inv;
  int i1 = 0; float p1 = p[0];
  #pragma unroll
  for (int e = 1; e < EDIM; ++e) if (p[e] > p1) { p1 = p[e]; i1 = e; }
  int i2 = (i1 == 0) ? 1 : 0; float p2 = p[i2];
  #pragma unroll
  for (int e = 0; e < EDIM; ++e) if (e != i1 && p[e] > p2) { p2 = p[e]; i2 = e; }
  float gs = 1.f / (p1 + p2);
  if (lane == 0) {
    eidx[2 * t] = i1; eidx[2 * t + 1] = i2;
    gates[2 * t] = p1 * gs; gates[2 * t + 1] = p2 * gs;
    #pragma unroll
    for (int e = 0; e < EDIM; ++e) wps[wv][e] = p[e];
  }
  __syncthreads();
  if (tid < EDIM)
    bps[blockIdx.x * EDIM + tid] = wps[0][tid] + wps[1][tid] + wps[2][tid] + wps[3][tid];
}

// -------- merged routing: count + scan + lb_loss + positions in ONE single-block kernel --------
// Replaces count_k/scan_k/pos_k (3 launches -> 1). Per-chunk ballot logic is identical to
// the split version, chunks processed in the same order -> bit-identical positions.
__global__ __launch_bounds__(256)
void route_k(const int* __restrict__ eidx, const float* __restrict__ gates,
             const float* __restrict__ bps, int* __restrict__ posa,
             float* __restrict__ wslot, int* __restrict__ rowsNeeded,
             float* __restrict__ lb_out) {
  __shared__ int cc_s[32][EDIM];
  __shared__ int cb_s[32][EDIM];
  __shared__ int wcnt[4][EDIM];
  __shared__ float red[32][EDIM];
  __shared__ int cnt_s[EDIM];
  const int tid = threadIdx.x, lane = tid & 63, wv = tid >> 6;
  // ---- count per chunk (wave ballots, no atomics)
  for (int c = 0; c < 32; ++c) {
    const int e = eidx[c * 256 + tid];
    #pragma unroll
    for (int ee = 0; ee < EDIM; ++ee) {
      unsigned long long m = __ballot(e == ee);
      if (lane == 0) wcnt[wv][ee] = __popcll(m);
    }
    __syncthreads();
    if (tid < EDIM) cc_s[c][tid] = wcnt[0][tid] + wcnt[1][tid] + wcnt[2][tid] + wcnt[3][tid];
    __syncthreads();
  }
  // ---- bps tree-reduction (router prob sums)
  {
    const int e = tid & 7, g = tid >> 3;
    float s = 0.f;
    for (int j = 0; j < 32; ++j) s += bps[(g + 32 * j) * EDIM + e];
    red[g][e] = s;
    __syncthreads();
    for (int st = 16; st >= 1; st >>= 1) {
      if (g < st) red[g][e] += red[g + st][e];
      __syncthreads();
    }
  }
  // ---- exclusive scan of chunk counts, totals
  if (tid < EDIM) {
    int base = 0;
    for (int c = 0; c < 32; ++c) { cb_s[c][tid] = base; base += cc_s[c][tid]; }
    cnt_s[tid] = base;
    rowsNeeded[tid] = base < CAPD ? base : CAPD;
  }
  __syncthreads();
  if (tid == 0) {
    float lb = 0.f;
    for (int ee = 0; ee < EDIM; ++ee)
      lb += (red[0][ee] / (float)TDIM) * ((float)cnt_s[ee] / (float)NSLOT);
    lb_out[0] = lb * (float)EDIM;
  }
  // ---- positions (same ballot pattern as the old pos_k, chunk-sequential)
  const unsigned long long below = (1ull << lane) - 1ull;
  for (int c = 0; c < 32; ++c) {
    const int slot = c * 256 + tid;
    const int e = eidx[slot];
    int wavepos = 0;
    #pragma unroll
    for (int ee = 0; ee < EDIM; ++ee) {
      unsigned long long m = __ballot(e == ee);
      if (lane == 0) wcnt[wv][ee] = __popcll(m);
      if (e == ee) wavepos = __popcll(m & below);
    }
    __syncthreads();
    int off = 0;
    for (int w = 0; w < wv; ++w) off += wcnt[w][e];
    const int pos = cb_s[c][e] + off + wavepos;
    posa[slot] = pos;
    wslot[slot] = (pos < CAPD) ? gates[slot] : 0.f;
    __syncthreads();                       // wcnt reused next chunk
  }
}

// ---------------- scatter: one block per TOKEN, x-row read once, both slots written ----------------
__global__ void scatter2_k(const float* __restrict__ x, const int* __restrict__ eidx,
                           const int* __restrict__ posa, f16* __restrict__ buf) {
  const int t = blockIdx.x, lane = threadIdx.x;   // 64 threads
  const int s0 = 2 * t, s1 = 2 * t + 1;
  const int p0 = posa[s0], p1 = posa[s1];
  const int e0 = eidx[s0], e1 = eidx[s1];
  const float4* src = (const float4*)(x + (size_t)t * DDIM);
  f16x4* d0 = (f16x4*)(buf + ((size_t)e0 * CAPD + p0) * DDIM);
  f16x4* d1 = (f16x4*)(buf + ((size_t)e1 * CAPD + p1) * DDIM);
  const bool w0 = p0 < CAPD, w1 = p1 < CAPD;
  #pragma unroll
  for (int j = 0; j < DDIM / 4 / 64; ++j) {
    float4 v = src[j * 64 + lane];
    f16x4 o; o.x = (f16)v.x; o.y = (f16)v.y; o.z = (f16)v.z; o.w = (f16)v.w;
    if (w0) d0[j * 64 + lane] = o;
    if (w1) d1[j * 64 + lane] = o;
  }
}

// ============ 128x128 f16 MFMA GEMM — r14 structure (best verified: 295 us) ============
// Single 32KB buffer, full-drain __syncthreads K-loop, 4 blocks/CU, T2 swizzle,
// L2-banded 1-D grid (e = wg&7 -> XCD-affine; NTH band keeps per-expert B set <= 4MB).
#define STAGE(hh, g) do { \
    const f16* s_ = sP[hh] + (g) * 64; \
    char* d_ = smem + (hh) * 8192 + wv * 1024; \
    gload16(s_, d_); \
    gload16(s_ + (size_t)32 * LD, d_ + 4096); \
  } while (0)

template<int KLEN, int LD, int N, int GELU, int NTH, int NKS, int NMT>
__global__ __launch_bounds__(256, 4)
void gemm128s(const f16* __restrict__ A, const f16* __restrict__ Bt,
              const float* __restrict__ bias, f16* __restrict__ C, size_t pstride,
              const int* __restrict__ rowsNeeded) {
  constexpr int NTT = KLEN / 64;           // K-tiles
  __shared__ __align__(128) char smem[32768];
  const int wg = blockIdx.x;
  const int e = wg & 7;
  const int r = wg >> 3;
  const int ntl = r % NTH;
  const int ks = (r / NTH) % NKS;
  const int mt = (r / (NTH * NKS)) % NMT;
  const int nth = r / (NTH * NKS * NMT);
  const int nt = nth * NTH + ntl;
  if (mt * 128 >= rowsNeeded[e]) return;
  const int tid = threadIdx.x, lane = tid & 63, wv = tid >> 6;   // wv 0..3
  const int wr = wv >> 1, wc = wv & 1;     // 2 x 2 wave grid, per-wave 64x64 out
  const int ro = lane & 15, q4 = (lane >> 4) * 4;
  const int ko0b = (lane >> 4) * 16;       // k-offset bytes within 128B row
  const f16* aBase = A + ((size_t)e * CAPD + (size_t)mt * 128) * LD + (size_t)ks * KLEN;
  const f16* bBase = Bt + ((size_t)e * N + (size_t)nt * 128) * LD + (size_t)ks * KLEN;
  const int row0 = tid >> 3;               // 0..31 (second gload does row0+32)
  const int sw0 = ((tid & 7) ^ (row0 & 7)) * 8;   // pre-swizzled source col (elements)

  const f16* sP[4];
  sP[0] = aBase + (size_t)row0 * LD + sw0;
  sP[1] = sP[0] + (size_t)64 * LD;
  sP[2] = bBase + (size_t)row0 * LD + sw0;
  sP[3] = sP[2] + (size_t)64 * LD;

  // hoisted LDS read byte-offsets
  int aoffs[4][2], boffs[4][2];
  #pragma unroll
  for (int m = 0; m < 4; ++m)
    #pragma unroll
    for (int k = 0; k < 2; ++k) {
      const int rh = wr * 64 + m * 16 + ro;
      aoffs[m][k] = rh * 128 + ((k * 64 + ko0b) ^ ((rh & 7) << 4));
      const int rb = wc * 64 + m * 16 + ro;
      boffs[m][k] = 16384 + rb * 128 + ((k * 64 + ko0b) ^ ((rb & 7) << 4));
    }

  f32x4 acc[4][4];
  #pragma unroll
  for (int m = 0; m < 4; ++m)
    #pragma unroll
    for (int n = 0; n < 4; ++n) acc[m][n] = (f32x4){0.f, 0.f, 0.f, 0.f};

  #pragma unroll 1
  for (int t = 0; t < NTT; ++t) {
    STAGE(0, t); STAGE(1, t); STAGE(2, t); STAGE(3, t);
    __syncthreads();                        // drains vmcnt(0): tile staged, all waves
    f16x8 af[4][2], bf[4][2];
    #pragma unroll
    for (int m = 0; m < 4; ++m)
      #pragma unroll
      for (int k = 0; k < 2; ++k) {
        af[m][k] = *(const f16x8*)(smem + aoffs[m][k]);
        bf[m][k] = *(const f16x8*)(smem + boffs[m][k]);
      }
    #pragma unroll
    for (int k = 0; k < 2; ++k)
      #pragma unroll
      for (int m = 0; m < 4; ++m)
        #pragma unroll
        for (int n = 0; n < 4; ++n)
          acc[m][n] = __builtin_amdgcn_mfma_f32_16x16x32_f16(af[m][k], bf[n][k], acc[m][n], 0, 0, 0);
    __syncthreads();                        // drains lgkmcnt: safe to overwrite LDS
  }

  // ---- epilogue: per-wave 8KB LDS region, swizzled conflict-free, coalesced stores
  float bv[4];
  #pragma unroll
  for (int n = 0; n < 4; ++n)
    bv[n] = (ks == 0) ? bias[e * N + nt * 128 + wc * 64 + n * 16 + ro] : 0.f;
  f16* Ct = (f16*)(smem + wv * 8192);       // [64][64] f16, col-byte ^= ((row>>2)&3)<<5
  #pragma unroll
  for (int m = 0; m < 4; ++m)
    #pragma unroll
    for (int n = 0; n < 4; ++n)
      #pragma unroll
      for (int i = 0; i < 4; ++i) {
        const int row = m * 16 + q4 + i;
        float v = acc[m][n][i] + bv[n];
        if (GELU) v = gelu_fast(v);
        *(f16*)((char*)Ct + row * 128 + (((n * 16 + ro) * 2) ^ (((row >> 2) & 3) << 5))) = (f16)v;
      }
  asm volatile("s_waitcnt lgkmcnt(0)" ::: "memory");
  __builtin_amdgcn_sched_barrier(0);
  f16* Cp = C + (size_t)ks * pstride;
  const size_t crow0 = (size_t)e * CAPD + mt * 128 + wr * 64;
  const int ccol0 = nt * 128 + wc * 64;
  #pragma unroll
  for (int j = 0; j < 8; ++j) {
    const int idx = j * 64 + lane;
    const int rr = idx >> 3, c2 = (idx & 7) * 16;
    f16x8 v = *(const f16x8*)((const char*)Ct + rr * 128 + (c2 ^ (((rr >> 2) & 3) << 5)));
    *(f16x8*)(Cp + (crow0 + rr) * N + ccol0 + (idx & 7) * 8) = v;
  }
}

// ---------------- combine: out[t] = sum_k wslot * (partA[row] + partB[row]) ----------------
__global__ void combine_k(const f16* __restrict__ pA, const f16* __restrict__ pB,
                          const int* __restrict__ eidx, const int* __restrict__ posa,
                          const float* __restrict__ wslot, float* __restrict__ out) {
  const int t = blockIdx.x, tid = threadIdx.x;
  const int s0 = 2 * t, s1 = 2 * t + 1;
  const int e0 = eidx[s0], e1 = eidx[s1];
  int p0 = posa[s0]; p0 = p0 < CAPD - 1 ? p0 : CAPD - 1;
  int p1 = posa[s1]; p1 = p1 < CAPD - 1 ? p1 : CAPD - 1;
  const float g0 = wslot[s0], g1 = wslot[s1];
  const size_t o0 = ((size_t)e0 * CAPD + p0) * DDIM;
  const size_t o1 = ((size_t)e1 * CAPD + p1) * DDIM;
  const f16x2* r0a = (const f16x2*)(pA + o0);
  const f16x2* r0b = (const f16x2*)(pB + o0);
  const f16x2* r1a = (const f16x2*)(pA + o1);
  const f16x2* r1b = (const f16x2*)(pB + o1);
  float2* o = (float2*)(out + (size_t)t * DDIM);
  #pragma unroll
  for (int j = tid; j < DDIM / 2; j += 256) {
    f16x2 a0 = r0a[j], a1 = r0b[j], b0 = r1a[j], b1 = r1b[j];
    o[j] = make_float2(
        g0 * ((float)a0.x + (float)a1.x) + g1 * ((float)b0.x + (float)b1.x),
        g0 * ((float)a0.y + (float)a1.y) + g1 * ((float)b0.y + (float)b1.y));
  }
}

extern "C" void kernel_launch(void* const* d_in, const int* in_sizes, int n_in,
                              void* d_out, int out_size, void* d_ws, size_t ws_size,
                              hipStream_t stream) {
  (void)in_sizes; (void)n_in; (void)out_size; (void)ws_size;
  const float* x  = (const float*)d_in[0];
  const float* rw = (const float*)d_in[1];
  const float* w1 = (const float*)d_in[2];
  const float* b1 = (const float*)d_in[3];
  const float* w2 = (const float*)d_in[4];
  const float* b2 = (const float*)d_in[5];
  float* out = (float*)d_out;

  char* ws = (char*)d_ws;
  size_t off = 0;
  auto alloc = [&](size_t b) { void* p = ws + off; off += (b + 255) & ~(size_t)255; return p; };
  f16* w1t   = (f16*)alloc((size_t)EDIM * DDIM * HDIM * 2);   // (E,H,D)
  f16* w2t   = (f16*)alloc((size_t)EDIM * DDIM * HDIM * 2);   // (E,D,H)
  f16* buf   = (f16*)alloc((size_t)EDIM * CAPD * DDIM * 2);   // (E,CAP,D)
  f16* hbuf  = (f16*)alloc((size_t)EDIM * CAPD * HDIM * 2);   // (E,CAP,H)
  const size_t PSTRIDE = (size_t)EDIM * CAPD * DDIM;
  f16* outeA = (f16*)alloc(PSTRIDE * 2);                       // split-K partial 0
  f16* outeB = (f16*)alloc(PSTRIDE * 2);                       // split-K partial 1 (contiguous)
  int*   eidx   = (int*)alloc(NSLOT * 4);
  int*   posa   = (int*)alloc(NSLOT * 4);
  float* gatesA = (float*)alloc(NSLOT * 4);
  float* wslotA = (float*)alloc(NSLOT * 4);
  int*   rowsN  = (int*)alloc(EDIM * 4);
  float* bps    = (float*)alloc(NROUTERBLK * EDIM * 4);
  (void)outeB;

  // weight conversion (independent of routing chain)
  transpose_cvt<<<dim3(HDIM / 64, DDIM / 64, EDIM), 256, 0, stream>>>(w1, w1t, DDIM, HDIM);
  transpose_cvt<<<dim3(DDIM / 64, HDIM / 64, EDIM), 256, 0, stream>>>(w2, w2t, HDIM, DDIM);

  // routing chain: router -> merged count/scan/pos -> scatter
  router_k<<<NROUTERBLK, 256, 0, stream>>>(x, rw, eidx, gatesA, bps);
  route_k<<<1, 256, 0, stream>>>(eidx, gatesA, bps, posa, wslotA, rowsN,
                                 out + (size_t)TDIM * DDIM);
  scatter2_k<<<TDIM, 64, 0, stream>>>(x, eidx, posa, buf);

  // expert GEMM 1: (E,CAP,D) x (E,D,H) -> GELU -> (E,CAP,H)
  // banded grid: wg = e + 8*(ntl + 16*(mt + 16*nth)); NTH=16 (B half-set = 4MB = XCD L2)
  gemm128s<DDIM, DDIM, HDIM, 1, 16, 1, 16><<<4096, 256, 0, stream>>>(
      buf, w1t, b1, hbuf, 0, rowsN);

  // expert GEMM 2, split-K=2 in ONE dispatch; B set already L2-fits
  gemm128s<HDIM / 2, HDIM, DDIM, 0, 8, 2, 16><<<2048, 256, 0, stream>>>(
      hbuf, w2t, b2, outeA, PSTRIDE, rowsN);

  // combine
  combine_k<<<TDIM, 256, 0, stream>>>(outeA, outeA + PSTRIDE, eidx, posa, wslotA, out);
}

// Round 18
// 297.357 us; speedup vs baseline: 1.1299x; 1.1299x over previous
//
#include <hip/hip_runtime.h>
#include <cstdint>
#include <cstddef>

#define TDIM 4096       // B*S tokens
#define DDIM 1024
#define HDIM 4096
#define EDIM 8
#define CAPD 2048
#define NSLOT 8192      // T*K
#define NROUTERBLK 1024

typedef _Float16 f16;
typedef _Float16 f16x2 __attribute__((ext_vector_type(2)));
typedef _Float16 f16x4 __attribute__((ext_vector_type(4)));
typedef _Float16 f16x8 __attribute__((ext_vector_type(8)));
typedef float f32x4 __attribute__((ext_vector_type(4)));

__device__ __forceinline__ void gload16(const void* g, void* l) {
  __builtin_amdgcn_global_load_lds(
      (const __attribute__((address_space(1))) unsigned int*)g,
      (__attribute__((address_space(3))) unsigned int*)l, 16, 0, 0);
}

__device__ __forceinline__ float gelu_fast(float x) {
  float y = 1.5957691216057308f * (x + 0.044715f * x * x * x);
  y = fminf(y, 60.f);
  float e = __expf(y);
  return x * e * __builtin_amdgcn_rcpf(e + 1.f);
}

// ------- merged transpose+cvt for BOTH weights in one dispatch (z<8: w1, z>=8: w2) -------
// w1: (E,DDIM,HDIM)->(E,HDIM,DDIM); w2: (E,HDIM,DDIM)->(E,DDIM,HDIM). Both sub-grids
// fully parallel (r17 lesson: merge launches, never serialize parallel work).
__global__ __launch_bounds__(256)
void transpose2_cvt(const float* __restrict__ w1, f16* __restrict__ w1t,
                    const float* __restrict__ w2, f16* __restrict__ w2t) {
  __shared__ float tile[64][65];
  const int z = blockIdx.z;
  const float* src; f16* dst; int R, C, c0, r0, e;
  if (z < EDIM) {
    e = z; src = w1; dst = w1t; R = DDIM; C = HDIM;
    c0 = blockIdx.x * 64; r0 = blockIdx.y * 64;          // bx<64 -> c0<4096; by<16 -> r0<1024
  } else {
    e = z - EDIM; src = w2; dst = w2t; R = HDIM; C = DDIM;
    c0 = blockIdx.y * 64; r0 = blockIdx.x * 64;          // by<16 -> c0<1024; bx<64 -> r0<4096
  }
  const int tid = threadIdx.x;
  const float* s = src + (size_t)e * R * C;
  f16* d = dst + (size_t)e * R * C;
  #pragma unroll
  for (int p = 0; p < 4; ++p) {
    const int row = p * 16 + (tid >> 4);
    const int col = (tid & 15) * 4;
    float4 v = *(const float4*)(s + (size_t)(r0 + row) * C + c0 + col);
    tile[row][col] = v.x; tile[row][col + 1] = v.y;
    tile[row][col + 2] = v.z; tile[row][col + 3] = v.w;
  }
  __syncthreads();
  #pragma unroll
  for (int p = 0; p < 4; ++p) {
    const int crow = p * 16 + (tid >> 4);
    const int q = (tid & 15) * 4;
    f16x4 o;
    #pragma unroll
    for (int j = 0; j < 4; ++j) o[j] = (f16)tile[q + j][crow];
    *(f16x4*)(d + (size_t)(c0 + crow) * R + r0 + q) = o;
  }
}

// ---------------- router ----------------
__global__ void router_k(const float* __restrict__ x, const float* __restrict__ rw,
                         int* __restrict__ eidx, float* __restrict__ gates,
                         float* __restrict__ bps) {
  __shared__ float lrw[EDIM * DDIM];
  __shared__ float wps[4][EDIM];
  const int tid = threadIdx.x, lane = tid & 63, wv = tid >> 6;
  for (int i = tid; i < EDIM * DDIM; i += 256) lrw[i] = rw[i];
  __syncthreads();
  const int t = blockIdx.x * 4 + wv;
  float acc[EDIM];
  #pragma unroll
  for (int e = 0; e < EDIM; ++e) acc[e] = 0.f;
  const float* xr = x + (size_t)t * DDIM;
  #pragma unroll
  for (int j = 0; j < DDIM / 64; ++j) {
    float xv = xr[j * 64 + lane];
    #pragma unroll
    for (int e = 0; e < EDIM; ++e) acc[e] += xv * lrw[e * DDIM + j * 64 + lane];
  }
  #pragma unroll
  for (int off = 32; off >= 1; off >>= 1) {
    #pragma unroll
    for (int e = 0; e < EDIM; ++e) acc[e] += __shfl_xor(acc[e], off);
  }
  float mx = acc[0];
  #pragma unroll
  for (int e = 1; e < EDIM; ++e) mx = fmaxf(mx, acc[e]);
  float p[EDIM], s = 0.f;
  #pragma unroll
  for (int e = 0; e < EDIM; ++e) { p[e] = expf(acc[e] - mx); s += p[e]; }
  float inv = 1.f / s;
  #pragma unroll
  for (int e = 0; e < EDIM; ++e) p[e] *= inv;
  int i1 = 0; float p1 = p[0];
  #pragma unroll
  for (int e = 1; e < EDIM; ++e) if (p[e] > p1) { p1 = p[e]; i1 = e; }
  int i2 = (i1 == 0) ? 1 : 0; float p2 = p[i2];
  #pragma unroll
  for (int e = 0; e < EDIM; ++e) if (e != i1 && p[e] > p2) { p2 = p[e]; i2 = e; }
  float gs = 1.f / (p1 + p2);
  if (lane == 0) {
    eidx[2 * t] = i1; eidx[2 * t + 1] = i2;
    gates[2 * t] = p1 * gs; gates[2 * t + 1] = p2 * gs;
    #pragma unroll
    for (int e = 0; e < EDIM; ++e) wps[wv][e] = p[e];
  }
  __syncthreads();
  if (tid < EDIM)
    bps[blockIdx.x * EDIM + tid] = wps[0][tid] + wps[1][tid] + wps[2][tid] + wps[3][tid];
}

// ---------------- per-chunk expert histogram ----------------
__global__ void count_k(const int* __restrict__ eidx, int* __restrict__ cc) {
  __shared__ int h[EDIM];
  const int tid = threadIdx.x;
  if (tid < EDIM) h[tid] = 0;
  __syncthreads();
  atomicAdd(&h[eidx[blockIdx.x * 256 + tid]], 1);
  __syncthreads();
  if (tid < EDIM) cc[blockIdx.x * EDIM + tid] = h[tid];
}

// ---------------- scan chunks, totals, lb_loss ----------------
__global__ void scan_k(const int* __restrict__ cc, const float* __restrict__ bps,
                       int* __restrict__ cb, int* __restrict__ counts,
                       int* __restrict__ rowsNeeded, float* __restrict__ lb_out) {
  __shared__ float red[32][EDIM];
  __shared__ int cnt_s[EDIM];
  const int tid = threadIdx.x;
  const int e = tid & 7, g = tid >> 3;
  float s = 0.f;
  for (int j = 0; j < 32; ++j) s += bps[(g + 32 * j) * EDIM + e];
  red[g][e] = s;
  __syncthreads();
  for (int st = 16; st >= 1; st >>= 1) {
    if (g < st) red[g][e] += red[g + st][e];
    __syncthreads();
  }
  if (tid < EDIM) {
    int base = 0;
    for (int c = 0; c < 32; ++c) { cb[c * EDIM + tid] = base; base += cc[c * EDIM + tid]; }
    counts[tid] = base;
    rowsNeeded[tid] = base < CAPD ? base : CAPD;
    cnt_s[tid] = base;
  }
  __syncthreads();
  if (tid == 0) {
    float lb = 0.f;
    for (int ee = 0; ee < EDIM; ++ee)
      lb += (red[0][ee] / (float)TDIM) * ((float)cnt_s[ee] / (float)NSLOT);
    lb_out[0] = lb * (float)EDIM;
  }
}

// ---------------- per-slot position via wave ballots (deterministic) ----------------
__global__ void pos_k(const int* __restrict__ eidx, const float* __restrict__ gates,
                      const int* __restrict__ cb, int* __restrict__ posa,
                      float* __restrict__ wslot) {
  __shared__ int wcnt[4][EDIM];
  const int tid = threadIdx.x, lane = tid & 63, wv = tid >> 6;
  const int slot = blockIdx.x * 256 + tid;
  const int e = eidx[slot];
  const unsigned long long below = (1ull << lane) - 1ull;
  int wavepos = 0;
  #pragma unroll
  for (int ee = 0; ee < EDIM; ++ee) {
    unsigned long long m = __ballot(e == ee);
    if (lane == 0) wcnt[wv][ee] = __popcll(m);
    if (e == ee) wavepos = __popcll(m & below);
  }
  __syncthreads();
  int off = 0;
  for (int w = 0; w < wv; ++w) off += wcnt[w][e];
  const int pos = cb[blockIdx.x * EDIM + e] + off + wavepos;
  posa[slot] = pos;
  wslot[slot] = (pos < CAPD) ? gates[slot] : 0.f;
}

// ---------------- scatter: one block per TOKEN, x-row read once, both slots written ----------------
__global__ void scatter2_k(const float* __restrict__ x, const int* __restrict__ eidx,
                           const int* __restrict__ posa, f16* __restrict__ buf) {
  const int t = blockIdx.x, lane = threadIdx.x;   // 64 threads
  const int s0 = 2 * t, s1 = 2 * t + 1;
  const int p0 = posa[s0], p1 = posa[s1];
  const int e0 = eidx[s0], e1 = eidx[s1];
  const float4* src = (const float4*)(x + (size_t)t * DDIM);
  f16x4* d0 = (f16x4*)(buf + ((size_t)e0 * CAPD + p0) * DDIM);
  f16x4* d1 = (f16x4*)(buf + ((size_t)e1 * CAPD + p1) * DDIM);
  const bool w0 = p0 < CAPD, w1 = p1 < CAPD;
  #pragma unroll
  for (int j = 0; j < DDIM / 4 / 64; ++j) {
    float4 v = src[j * 64 + lane];
    f16x4 o; o.x = (f16)v.x; o.y = (f16)v.y; o.z = (f16)v.z; o.w = (f16)v.w;
    if (w0) d0[j * 64 + lane] = o;
    if (w1) d1[j * 64 + lane] = o;
  }
}

// ============ 128x128 f16 MFMA GEMM — r14 structure (best verified: 295 us) ============
// Single 32KB buffer, full-drain __syncthreads K-loop, 4 blocks/CU, T2 swizzle,
// L2-banded 1-D grid (e = wg&7 -> XCD-affine; NTH band keeps per-expert B set <= 4MB).
#define STAGE(hh, g) do { \
    const f16* s_ = sP[hh] + (g) * 64; \
    char* d_ = smem + (hh) * 8192 + wv * 1024; \
    gload16(s_, d_); \
    gload16(s_ + (size_t)32 * LD, d_ + 4096); \
  } while (0)

template<int KLEN, int LD, int N, int GELU, int NTH, int NKS, int NMT>
__global__ __launch_bounds__(256, 4)
void gemm128s(const f16* __restrict__ A, const f16* __restrict__ Bt,
              const float* __restrict__ bias, f16* __restrict__ C, size_t pstride,
              const int* __restrict__ rowsNeeded) {
  constexpr int NTT = KLEN / 64;           // K-tiles
  __shared__ __align__(128) char smem[32768];
  const int wg = blockIdx.x;
  const int e = wg & 7;
  const int r = wg >> 3;
  const int ntl = r % NTH;
  const int ks = (r / NTH) % NKS;
  const int mt = (r / (NTH * NKS)) % NMT;
  const int nth = r / (NTH * NKS * NMT);
  const int nt = nth * NTH + ntl;
  if (mt * 128 >= rowsNeeded[e]) return;
  const int tid = threadIdx.x, lane = tid & 63, wv = tid >> 6;   // wv 0..3
  const int wr = wv >> 1, wc = wv & 1;     // 2 x 2 wave grid, per-wave 64x64 out
  const int ro = lane & 15, q4 = (lane >> 4) * 4;
  const int ko0b = (lane >> 4) * 16;       // k-offset bytes within 128B row
  const f16* aBase = A + ((size_t)e * CAPD + (size_t)mt * 128) * LD + (size_t)ks * KLEN;
  const f16* bBase = Bt + ((size_t)e * N + (size_t)nt * 128) * LD + (size_t)ks * KLEN;
  const int row0 = tid >> 3;               // 0..31 (second gload does row0+32)
  const int sw0 = ((tid & 7) ^ (row0 & 7)) * 8;   // pre-swizzled source col (elements)

  const f16* sP[4];
  sP[0] = aBase + (size_t)row0 * LD + sw0;
  sP[1] = sP[0] + (size_t)64 * LD;
  sP[2] = bBase + (size_t)row0 * LD + sw0;
  sP[3] = sP[2] + (size_t)64 * LD;

  // hoisted LDS read byte-offsets
  int aoffs[4][2], boffs[4][2];
  #pragma unroll
  for (int m = 0; m < 4; ++m)
    #pragma unroll
    for (int k = 0; k < 2; ++k) {
      const int rh = wr * 64 + m * 16 + ro;
      aoffs[m][k] = rh * 128 + ((k * 64 + ko0b) ^ ((rh & 7) << 4));
      const int rb = wc * 64 + m * 16 + ro;
      boffs[m][k] = 16384 + rb * 128 + ((k * 64 + ko0b) ^ ((rb & 7) << 4));
    }

  f32x4 acc[4][4];
  #pragma unroll
  for (int m = 0; m < 4; ++m)
    #pragma unroll
    for (int n = 0; n < 4; ++n) acc[m][n] = (f32x4){0.f, 0.f, 0.f, 0.f};

  #pragma unroll 1
  for (int t = 0; t < NTT; ++t) {
    STAGE(0, t); STAGE(1, t); STAGE(2, t); STAGE(3, t);
    __syncthreads();                        // drains vmcnt(0): tile staged, all waves
    f16x8 af[4][2], bf[4][2];
    #pragma unroll
    for (int m = 0; m < 4; ++m)
      #pragma unroll
      for (int k = 0; k < 2; ++k) {
        af[m][k] = *(const f16x8*)(smem + aoffs[m][k]);
        bf[m][k] = *(const f16x8*)(smem + boffs[m][k]);
      }
    #pragma unroll
    for (int k = 0; k < 2; ++k)
      #pragma unroll
      for (int m = 0; m < 4; ++m)
        #pragma unroll
        for (int n = 0; n < 4; ++n)
          acc[m][n] = __builtin_amdgcn_mfma_f32_16x16x32_f16(af[m][k], bf[n][k], acc[m][n], 0, 0, 0);
    __syncthreads();                        // drains lgkmcnt: safe to overwrite LDS
  }

  // ---- epilogue: per-wave 8KB LDS region, swizzled conflict-free, coalesced stores
  float bv[4];
  #pragma unroll
  for (int n = 0; n < 4; ++n)
    bv[n] = (ks == 0) ? bias[e * N + nt * 128 + wc * 64 + n * 16 + ro] : 0.f;
  f16* Ct = (f16*)(smem + wv * 8192);       // [64][64] f16, col-byte ^= ((row>>2)&3)<<5
  #pragma unroll
  for (int m = 0; m < 4; ++m)
    #pragma unroll
    for (int n = 0; n < 4; ++n)
      #pragma unroll
      for (int i = 0; i < 4; ++i) {
        const int row = m * 16 + q4 + i;
        float v = acc[m][n][i] + bv[n];
        if (GELU) v = gelu_fast(v);
        *(f16*)((char*)Ct + row * 128 + (((n * 16 + ro) * 2) ^ (((row >> 2) & 3) << 5))) = (f16)v;
      }
  asm volatile("s_waitcnt lgkmcnt(0)" ::: "memory");
  __builtin_amdgcn_sched_barrier(0);
  f16* Cp = C + (size_t)ks * pstride;
  const size_t crow0 = (size_t)e * CAPD + mt * 128 + wr * 64;
  const int ccol0 = nt * 128 + wc * 64;
  #pragma unroll
  for (int j = 0; j < 8; ++j) {
    const int idx = j * 64 + lane;
    const int rr = idx >> 3, c2 = (idx & 7) * 16;
    f16x8 v = *(const f16x8*)((const char*)Ct + rr * 128 + (c2 ^ (((rr >> 2) & 3) << 5)));
    *(f16x8*)(Cp + (crow0 + rr) * N + ccol0 + (idx & 7) * 8) = v;
  }
}

// ---------------- combine: out[t] = sum_k wslot * (partA[row] + partB[row]) ----------------
__global__ void combine_k(const f16* __restrict__ pA, const f16* __restrict__ pB,
                          const int* __restrict__ eidx, const int* __restrict__ posa,
                          const float* __restrict__ wslot, float* __restrict__ out) {
  const int t = blockIdx.x, tid = threadIdx.x;
  const int s0 = 2 * t, s1 = 2 * t + 1;
  const int e0 = eidx[s0], e1 = eidx[s1];
  int p0 = posa[s0]; p0 = p0 < CAPD - 1 ? p0 : CAPD - 1;
  int p1 = posa[s1]; p1 = p1 < CAPD - 1 ? p1 : CAPD - 1;
  const float g0 = wslot[s0], g1 = wslot[s1];
  const size_t o0 = ((size_t)e0 * CAPD + p0) * DDIM;
  const size_t o1 = ((size_t)e1 * CAPD + p1) * DDIM;
  const f16x2* r0a = (const f16x2*)(pA + o0);
  const f16x2* r0b = (const f16x2*)(pB + o0);
  const f16x2* r1a = (const f16x2*)(pA + o1);
  const f16x2* r1b = (const f16x2*)(pB + o1);
  float2* o = (float2*)(out + (size_t)t * DDIM);
  #pragma unroll
  for (int j = tid; j < DDIM / 2; j += 256) {
    f16x2 a0 = r0a[j], a1 = r0b[j], b0 = r1a[j], b1 = r1b[j];
    o[j] = make_float2(
        g0 * ((float)a0.x + (float)a1.x) + g1 * ((float)b0.x + (float)b1.x),
        g0 * ((float)a0.y + (float)a1.y) + g1 * ((float)b0.y + (float)b1.y));
  }
}

extern "C" void kernel_launch(void* const* d_in, const int* in_sizes, int n_in,
                              void* d_out, int out_size, void* d_ws, size_t ws_size,
                              hipStream_t stream) {
  (void)in_sizes; (void)n_in; (void)out_size; (void)ws_size;
  const float* x  = (const float*)d_in[0];
  const float* rw = (const float*)d_in[1];
  const float* w1 = (const float*)d_in[2];
  const float* b1 = (const float*)d_in[3];
  const float* w2 = (const float*)d_in[4];
  const float* b2 = (const float*)d_in[5];
  float* out = (float*)d_out;

  char* ws = (char*)d_ws;
  size_t off = 0;
  auto alloc = [&](size_t b) { void* p = ws + off; off += (b + 255) & ~(size_t)255; return p; };
  f16* w1t   = (f16*)alloc((size_t)EDIM * DDIM * HDIM * 2);   // (E,H,D)
  f16* w2t   = (f16*)alloc((size_t)EDIM * DDIM * HDIM * 2);   // (E,D,H)
  f16* buf   = (f16*)alloc((size_t)EDIM * CAPD * DDIM * 2);   // (E,CAP,D)
  f16* hbuf  = (f16*)alloc((size_t)EDIM * CAPD * HDIM * 2);   // (E,CAP,H)
  const size_t PSTRIDE = (size_t)EDIM * CAPD * DDIM;
  f16* outeA = (f16*)alloc(PSTRIDE * 2);                       // split-K partial 0
  f16* outeB = (f16*)alloc(PSTRIDE * 2);                       // split-K partial 1 (contiguous)
  int*   eidx   = (int*)alloc(NSLOT * 4);
  int*   posa   = (int*)alloc(NSLOT * 4);
  float* gatesA = (float*)alloc(NSLOT * 4);
  float* wslotA = (float*)alloc(NSLOT * 4);
  int*   cc     = (int*)alloc(32 * EDIM * 4);
  int*   cb     = (int*)alloc(32 * EDIM * 4);
  int*   counts = (int*)alloc(EDIM * 4);
  int*   rowsN  = (int*)alloc(EDIM * 4);
  float* bps    = (float*)alloc(NROUTERBLK * EDIM * 4);
  (void)outeB;

  // weight conversion: both transposes in ONE dispatch (z<8: w1, z>=8: w2)
  transpose2_cvt<<<dim3(HDIM / 64, DDIM / 64, 2 * EDIM), 256, 0, stream>>>(w1, w1t, w2, w2t);

  // routing chain (split kernels — r17 showed merging serializes and loses 40 us)
  router_k<<<NROUTERBLK, 256, 0, stream>>>(x, rw, eidx, gatesA, bps);
  count_k<<<32, 256, 0, stream>>>(eidx, cc);
  scan_k<<<1, 256, 0, stream>>>(cc, bps, cb, counts, rowsN, out + (size_t)TDIM * DDIM);
  pos_k<<<32, 256, 0, stream>>>(eidx, gatesA, cb, posa, wslotA);
  scatter2_k<<<TDIM, 64, 0, stream>>>(x, eidx, posa, buf);

  // expert GEMM 1: (E,CAP,D) x (E,D,H) -> GELU -> (E,CAP,H)
  // banded grid: wg = e + 8*(ntl + 16*(mt + 16*nth)); NTH=16 (B half-set = 4MB = XCD L2)
  gemm128s<DDIM, DDIM, HDIM, 1, 16, 1, 16><<<4096, 256, 0, stream>>>(
      buf, w1t, b1, hbuf, 0, rowsN);

  // expert GEMM 2, split-K=2 in ONE dispatch; B set already L2-fits
  gemm128s<HDIM / 2, HDIM, DDIM, 0, 8, 2, 16><<<2048, 256, 0, stream>>>(
      hbuf, w2t, b2, outeA, PSTRIDE, rowsN);

  // combine
  combine_k<<<TDIM, 256, 0, stream>>>(outeA, outeA + PSTRIDE, eidx, posa, wslotA, out);
}

// Round 19
// 293.681 us; speedup vs baseline: 1.1440x; 1.0125x over previous
//
#include <hip/hip_runtime.h>
#include <cstdint>
#include <cstddef>

#define TDIM 4096       // B*S tokens
#define DDIM 1024
#define HDIM 4096
#define EDIM 8
#define CAPD 2048
#define NSLOT 8192      // T*K
#define NROUTERBLK 1024

typedef _Float16 f16;
typedef _Float16 f16x2 __attribute__((ext_vector_type(2)));
typedef _Float16 f16x4 __attribute__((ext_vector_type(4)));
typedef _Float16 f16x8 __attribute__((ext_vector_type(8)));
typedef float f32x4 __attribute__((ext_vector_type(4)));

__device__ __forceinline__ void gload16(const void* g, void* l) {
  __builtin_amdgcn_global_load_lds(
      (const __attribute__((address_space(1))) unsigned int*)g,
      (__attribute__((address_space(3))) unsigned int*)l, 16, 0, 0);
}

__device__ __forceinline__ float gelu_fast(float x) {
  float y = 1.5957691216057308f * (x + 0.044715f * x * x * x);
  y = fminf(y, 60.f);
  float e = __expf(y);
  return x * e * __builtin_amdgcn_rcpf(e + 1.f);
}

// ------- merged transpose+cvt, 128x64 tiles (r19): 16B/lane writes, 256B segments -------
// r18 profile: old transpose ran at 2.35 TB/s (f16x4 8B writes, 128B segments). New:
// f32 tile [128][65] (33KB); read = float4 256B row segments (8 iters); write = f16x8
// column-gather, 16 lanes x 16B = 256B contiguous per output row (4 iters).
// z<8: w1 (E,1024,4096)->(E,4096,1024); z>=8: w2 (E,4096,1024)->(E,1024,4096).
__global__ __launch_bounds__(256)
void transpose2_cvt(const float* __restrict__ w1, f16* __restrict__ w1t,
                    const float* __restrict__ w2, f16* __restrict__ w2t) {
  __shared__ float tile[128][65];
  const int z = blockIdx.z;
  const int id = blockIdx.y * 64 + blockIdx.x;   // 0..511 tile id
  const float* src; f16* dst; int R, C, rt, ct, e;
  if (z < EDIM) {
    e = z; src = w1; dst = w1t; R = DDIM; C = HDIM;
    ct = id & 63; rt = id >> 6;                  // 64 x 8 tiles
  } else {
    e = z - EDIM; src = w2; dst = w2t; R = HDIM; C = DDIM;
    ct = id & 15; rt = id >> 4;                  // 16 x 32 tiles
  }
  const int tid = threadIdx.x;
  const int r0 = rt * 128, c0 = ct * 64;
  const float* s = src + (size_t)e * R * C;
  f16* d = dst + (size_t)e * R * C;
  #pragma unroll
  for (int it = 0; it < 8; ++it) {
    const int idx = it * 256 + tid;
    const int row = idx >> 4, colq = (idx & 15) * 4;
    float4 v = *(const float4*)(s + (size_t)(r0 + row) * C + c0 + colq);
    tile[row][colq] = v.x; tile[row][colq + 1] = v.y;
    tile[row][colq + 2] = v.z; tile[row][colq + 3] = v.w;
  }
  __syncthreads();
  #pragma unroll
  for (int it = 0; it < 4; ++it) {
    const int idx = it * 256 + tid;
    const int c = idx >> 4, rw = (idx & 15) * 8;
    f16x8 o;
    #pragma unroll
    for (int j = 0; j < 8; ++j) o[j] = (f16)tile[rw + j][c];
    *(f16x8*)(d + (size_t)(c0 + c) * R + r0 + rw) = o;
  }
}

// ---------------- router ----------------
__global__ void router_k(const float* __restrict__ x, const float* __restrict__ rw,
                         int* __restrict__ eidx, float* __restrict__ gates,
                         float* __restrict__ bps) {
  __shared__ float lrw[EDIM * DDIM];
  __shared__ float wps[4][EDIM];
  const int tid = threadIdx.x, lane = tid & 63, wv = tid >> 6;
  for (int i = tid; i < EDIM * DDIM; i += 256) lrw[i] = rw[i];
  __syncthreads();
  const int t = blockIdx.x * 4 + wv;
  float acc[EDIM];
  #pragma unroll
  for (int e = 0; e < EDIM; ++e) acc[e] = 0.f;
  const float* xr = x + (size_t)t * DDIM;
  #pragma unroll
  for (int j = 0; j < DDIM / 64; ++j) {
    float xv = xr[j * 64 + lane];
    #pragma unroll
    for (int e = 0; e < EDIM; ++e) acc[e] += xv * lrw[e * DDIM + j * 64 + lane];
  }
  #pragma unroll
  for (int off = 32; off >= 1; off >>= 1) {
    #pragma unroll
    for (int e = 0; e < EDIM; ++e) acc[e] += __shfl_xor(acc[e], off);
  }
  float mx = acc[0];
  #pragma unroll
  for (int e = 1; e < EDIM; ++e) mx = fmaxf(mx, acc[e]);
  float p[EDIM], s = 0.f;
  #pragma unroll
  for (int e = 0; e < EDIM; ++e) { p[e] = expf(acc[e] - mx); s += p[e]; }
  float inv = 1.f / s;
  #pragma unroll
  for (int e = 0; e < EDIM; ++e) p[e] *= inv;
  int i1 = 0; float p1 = p[0];
  #pragma unroll
  for (int e = 1; e < EDIM; ++e) if (p[e] > p1) { p1 = p[e]; i1 = e; }
  int i2 = (i1 == 0) ? 1 : 0; float p2 = p[i2];
  #pragma unroll
  for (int e = 0; e < EDIM; ++e) if (e != i1 && p[e] > p2) { p2 = p[e]; i2 = e; }
  float gs = 1.f / (p1 + p2);
  if (lane == 0) {
    eidx[2 * t] = i1; eidx[2 * t + 1] = i2;
    gates[2 * t] = p1 * gs; gates[2 * t + 1] = p2 * gs;
    #pragma unroll
    for (int e = 0; e < EDIM; ++e) wps[wv][e] = p[e];
  }
  __syncthreads();
  if (tid < EDIM)
    bps[blockIdx.x * EDIM + tid] = wps[0][tid] + wps[1][tid] + wps[2][tid] + wps[3][tid];
}

// ---------------- per-chunk expert histogram ----------------
__global__ void count_k(const int* __restrict__ eidx, int* __restrict__ cc) {
  __shared__ int h[EDIM];
  const int tid = threadIdx.x;
  if (tid < EDIM) h[tid] = 0;
  __syncthreads();
  atomicAdd(&h[eidx[blockIdx.x * 256 + tid]], 1);
  __syncthreads();
  if (tid < EDIM) cc[blockIdx.x * EDIM + tid] = h[tid];
}

// ---------------- scan chunks, totals, lb_loss ----------------
__global__ void scan_k(const int* __restrict__ cc, const float* __restrict__ bps,
                       int* __restrict__ cb, int* __restrict__ counts,
                       int* __restrict__ rowsNeeded, float* __restrict__ lb_out) {
  __shared__ float red[32][EDIM];
  __shared__ int cnt_s[EDIM];
  const int tid = threadIdx.x;
  const int e = tid & 7, g = tid >> 3;
  float s = 0.f;
  for (int j = 0; j < 32; ++j) s += bps[(g + 32 * j) * EDIM + e];
  red[g][e] = s;
  __syncthreads();
  for (int st = 16; st >= 1; st >>= 1) {
    if (g < st) red[g][e] += red[g + st][e];
    __syncthreads();
  }
  if (tid < EDIM) {
    int base = 0;
    for (int c = 0; c < 32; ++c) { cb[c * EDIM + tid] = base; base += cc[c * EDIM + tid]; }
    counts[tid] = base;
    rowsNeeded[tid] = base < CAPD ? base : CAPD;
    cnt_s[tid] = base;
  }
  __syncthreads();
  if (tid == 0) {
    float lb = 0.f;
    for (int ee = 0; ee < EDIM; ++ee)
      lb += (red[0][ee] / (float)TDIM) * ((float)cnt_s[ee] / (float)NSLOT);
    lb_out[0] = lb * (float)EDIM;
  }
}

// ---------------- per-slot position via wave ballots (deterministic) ----------------
__global__ void pos_k(const int* __restrict__ eidx, const float* __restrict__ gates,
                      const int* __restrict__ cb, int* __restrict__ posa,
                      float* __restrict__ wslot) {
  __shared__ int wcnt[4][EDIM];
  const int tid = threadIdx.x, lane = tid & 63, wv = tid >> 6;
  const int slot = blockIdx.x * 256 + tid;
  const int e = eidx[slot];
  const unsigned long long below = (1ull << lane) - 1ull;
  int wavepos = 0;
  #pragma unroll
  for (int ee = 0; ee < EDIM; ++ee) {
    unsigned long long m = __ballot(e == ee);
    if (lane == 0) wcnt[wv][ee] = __popcll(m);
    if (e == ee) wavepos = __popcll(m & below);
  }
  __syncthreads();
  int off = 0;
  for (int w = 0; w < wv; ++w) off += wcnt[w][e];
  const int pos = cb[blockIdx.x * EDIM + e] + off + wavepos;
  posa[slot] = pos;
  wslot[slot] = (pos < CAPD) ? gates[slot] : 0.f;
}

// ---------------- scatter: one block per TOKEN, x-row read once, both slots written ----------------
__global__ void scatter2_k(const float* __restrict__ x, const int* __restrict__ eidx,
                           const int* __restrict__ posa, f16* __restrict__ buf) {
  const int t = blockIdx.x, lane = threadIdx.x;   // 64 threads
  const int s0 = 2 * t, s1 = 2 * t + 1;
  const int p0 = posa[s0], p1 = posa[s1];
  const int e0 = eidx[s0], e1 = eidx[s1];
  const float4* src = (const float4*)(x + (size_t)t * DDIM);
  f16x4* d0 = (f16x4*)(buf + ((size_t)e0 * CAPD + p0) * DDIM);
  f16x4* d1 = (f16x4*)(buf + ((size_t)e1 * CAPD + p1) * DDIM);
  const bool w0 = p0 < CAPD, w1 = p1 < CAPD;
  #pragma unroll
  for (int j = 0; j < DDIM / 4 / 64; ++j) {
    float4 v = src[j * 64 + lane];
    f16x4 o; o.x = (f16)v.x; o.y = (f16)v.y; o.z = (f16)v.z; o.w = (f16)v.w;
    if (w0) d0[j * 64 + lane] = o;
    if (w1) d1[j * 64 + lane] = o;
  }
}

// ============ 128x128 f16 MFMA GEMM — r14 structure (best verified: 295 us) ============
// Single 32KB buffer, full-drain __syncthreads K-loop, 4 blocks/CU, T2 swizzle,
// L2-banded 1-D grid (e = wg&7 -> XCD-affine; NTH band keeps per-expert B set <= 4MB).
#define STAGE(hh, g) do { \
    const f16* s_ = sP[hh] + (g) * 64; \
    char* d_ = smem + (hh) * 8192 + wv * 1024; \
    gload16(s_, d_); \
    gload16(s_ + (size_t)32 * LD, d_ + 4096); \
  } while (0)

template<int KLEN, int LD, int N, int GELU, int NTH, int NKS, int NMT>
__global__ __launch_bounds__(256, 4)
void gemm128s(const f16* __restrict__ A, const f16* __restrict__ Bt,
              const float* __restrict__ bias, f16* __restrict__ C, size_t pstride,
              const int* __restrict__ rowsNeeded) {
  constexpr int NTT = KLEN / 64;           // K-tiles
  __shared__ __align__(128) char smem[32768];
  const int wg = blockIdx.x;
  const int e = wg & 7;
  const int r = wg >> 3;
  const int ntl = r % NTH;
  const int ks = (r / NTH) % NKS;
  const int mt = (r / (NTH * NKS)) % NMT;
  const int nth = r / (NTH * NKS * NMT);
  const int nt = nth * NTH + ntl;
  if (mt * 128 >= rowsNeeded[e]) return;
  const int tid = threadIdx.x, lane = tid & 63, wv = tid >> 6;   // wv 0..3
  const int wr = wv >> 1, wc = wv & 1;     // 2 x 2 wave grid, per-wave 64x64 out
  const int ro = lane & 15, q4 = (lane >> 4) * 4;
  const int ko0b = (lane >> 4) * 16;       // k-offset bytes within 128B row
  const f16* aBase = A + ((size_t)e * CAPD + (size_t)mt * 128) * LD + (size_t)ks * KLEN;
  const f16* bBase = Bt + ((size_t)e * N + (size_t)nt * 128) * LD + (size_t)ks * KLEN;
  const int row0 = tid >> 3;               // 0..31 (second gload does row0+32)
  const int sw0 = ((tid & 7) ^ (row0 & 7)) * 8;   // pre-swizzled source col (elements)

  const f16* sP[4];
  sP[0] = aBase + (size_t)row0 * LD + sw0;
  sP[1] = sP[0] + (size_t)64 * LD;
  sP[2] = bBase + (size_t)row0 * LD + sw0;
  sP[3] = sP[2] + (size_t)64 * LD;

  // hoisted LDS read byte-offsets
  int aoffs[4][2], boffs[4][2];
  #pragma unroll
  for (int m = 0; m < 4; ++m)
    #pragma unroll
    for (int k = 0; k < 2; ++k) {
      const int rh = wr * 64 + m * 16 + ro;
      aoffs[m][k] = rh * 128 + ((k * 64 + ko0b) ^ ((rh & 7) << 4));
      const int rb = wc * 64 + m * 16 + ro;
      boffs[m][k] = 16384 + rb * 128 + ((k * 64 + ko0b) ^ ((rb & 7) << 4));
    }

  f32x4 acc[4][4];
  #pragma unroll
  for (int m = 0; m < 4; ++m)
    #pragma unroll
    for (int n = 0; n < 4; ++n) acc[m][n] = (f32x4){0.f, 0.f, 0.f, 0.f};

  #pragma unroll 1
  for (int t = 0; t < NTT; ++t) {
    STAGE(0, t); STAGE(1, t); STAGE(2, t); STAGE(3, t);
    __syncthreads();                        // drains vmcnt(0): tile staged, all waves
    f16x8 af[4][2], bf[4][2];
    #pragma unroll
    for (int m = 0; m < 4; ++m)
      #pragma unroll
      for (int k = 0; k < 2; ++k) {
        af[m][k] = *(const f16x8*)(smem + aoffs[m][k]);
        bf[m][k] = *(const f16x8*)(smem + boffs[m][k]);
      }
    #pragma unroll
    for (int k = 0; k < 2; ++k)
      #pragma unroll
      for (int m = 0; m < 4; ++m)
        #pragma unroll
        for (int n = 0; n < 4; ++n)
          acc[m][n] = __builtin_amdgcn_mfma_f32_16x16x32_f16(af[m][k], bf[n][k], acc[m][n], 0, 0, 0);
    __syncthreads();                        // drains lgkmcnt: safe to overwrite LDS
  }

  // ---- epilogue: per-wave 8KB LDS region, swizzled conflict-free, coalesced stores
  float bv[4];
  #pragma unroll
  for (int n = 0; n < 4; ++n)
    bv[n] = (ks == 0) ? bias[e * N + nt * 128 + wc * 64 + n * 16 + ro] : 0.f;
  f16* Ct = (f16*)(smem + wv * 8192);       // [64][64] f16, col-byte ^= ((row>>2)&3)<<5
  #pragma unroll
  for (int m = 0; m < 4; ++m)
    #pragma unroll
    for (int n = 0; n < 4; ++n)
      #pragma unroll
      for (int i = 0; i < 4; ++i) {
        const int row = m * 16 + q4 + i;
        float v = acc[m][n][i] + bv[n];
        if (GELU) v = gelu_fast(v);
        *(f16*)((char*)Ct + row * 128 + (((n * 16 + ro) * 2) ^ (((row >> 2) & 3) << 5))) = (f16)v;
      }
  asm volatile("s_waitcnt lgkmcnt(0)" ::: "memory");
  __builtin_amdgcn_sched_barrier(0);
  f16* Cp = C + (size_t)ks * pstride;
  const size_t crow0 = (size_t)e * CAPD + mt * 128 + wr * 64;
  const int ccol0 = nt * 128 + wc * 64;
  #pragma unroll
  for (int j = 0; j < 8; ++j) {
    const int idx = j * 64 + lane;
    const int rr = idx >> 3, c2 = (idx & 7) * 16;
    f16x8 v = *(const f16x8*)((const char*)Ct + rr * 128 + (c2 ^ (((rr >> 2) & 3) << 5)));
    *(f16x8*)(Cp + (crow0 + rr) * N + ccol0 + (idx & 7) * 8) = v;
  }
}

// ---------------- combine: out[t] = sum_k wslot * (partA[row] + partB[row]) ----------------
__global__ void combine_k(const f16* __restrict__ pA, const f16* __restrict__ pB,
                          const int* __restrict__ eidx, const int* __restrict__ posa,
                          const float* __restrict__ wslot, float* __restrict__ out) {
  const int t = blockIdx.x, tid = threadIdx.x;
  const int s0 = 2 * t, s1 = 2 * t + 1;
  const int e0 = eidx[s0], e1 = eidx[s1];
  int p0 = posa[s0]; p0 = p0 < CAPD - 1 ? p0 : CAPD - 1;
  int p1 = posa[s1]; p1 = p1 < CAPD - 1 ? p1 : CAPD - 1;
  const float g0 = wslot[s0], g1 = wslot[s1];
  const size_t o0 = ((size_t)e0 * CAPD + p0) * DDIM;
  const size_t o1 = ((size_t)e1 * CAPD + p1) * DDIM;
  const f16x2* r0a = (const f16x2*)(pA + o0);
  const f16x2* r0b = (const f16x2*)(pB + o0);
  const f16x2* r1a = (const f16x2*)(pA + o1);
  const f16x2* r1b = (const f16x2*)(pB + o1);
  float2* o = (float2*)(out + (size_t)t * DDIM);
  #pragma unroll
  for (int j = tid; j < DDIM / 2; j += 256) {
    f16x2 a0 = r0a[j], a1 = r0b[j], b0 = r1a[j], b1 = r1b[j];
    o[j] = make_float2(
        g0 * ((float)a0.x + (float)a1.x) + g1 * ((float)b0.x + (float)b1.x),
        g0 * ((float)a0.y + (float)a1.y) + g1 * ((float)b0.y + (float)b1.y));
  }
}

extern "C" void kernel_launch(void* const* d_in, const int* in_sizes, int n_in,
                              void* d_out, int out_size, void* d_ws, size_t ws_size,
                              hipStream_t stream) {
  (void)in_sizes; (void)n_in; (void)out_size; (void)ws_size;
  const float* x  = (const float*)d_in[0];
  const float* rw = (const float*)d_in[1];
  const float* w1 = (const float*)d_in[2];
  const float* b1 = (const float*)d_in[3];
  const float* w2 = (const float*)d_in[4];
  const float* b2 = (const float*)d_in[5];
  float* out = (float*)d_out;

  char* ws = (char*)d_ws;
  size_t off = 0;
  auto alloc = [&](size_t b) { void* p = ws + off; off += (b + 255) & ~(size_t)255; return p; };
  f16* w1t   = (f16*)alloc((size_t)EDIM * DDIM * HDIM * 2);   // (E,H,D)
  f16* w2t   = (f16*)alloc((size_t)EDIM * DDIM * HDIM * 2);   // (E,D,H)
  f16* buf   = (f16*)alloc((size_t)EDIM * CAPD * DDIM * 2);   // (E,CAP,D)
  f16* hbuf  = (f16*)alloc((size_t)EDIM * CAPD * HDIM * 2);   // (E,CAP,H)
  const size_t PSTRIDE = (size_t)EDIM * CAPD * DDIM;
  f16* outeA = (f16*)alloc(PSTRIDE * 2);                       // split-K partial 0
  f16* outeB = (f16*)alloc(PSTRIDE * 2);                       // split-K partial 1 (contiguous)
  int*   eidx   = (int*)alloc(NSLOT * 4);
  int*   posa   = (int*)alloc(NSLOT * 4);
  float* gatesA = (float*)alloc(NSLOT * 4);
  float* wslotA = (float*)alloc(NSLOT * 4);
  int*   cc     = (int*)alloc(32 * EDIM * 4);
  int*   cb     = (int*)alloc(32 * EDIM * 4);
  int*   counts = (int*)alloc(EDIM * 4);
  int*   rowsN  = (int*)alloc(EDIM * 4);
  float* bps    = (float*)alloc(NROUTERBLK * EDIM * 4);
  (void)outeB;

  // weight conversion: both transposes in ONE dispatch, 128x64 tiles (512 tiles each side)
  transpose2_cvt<<<dim3(64, 8, 2 * EDIM), 256, 0, stream>>>(w1, w1t, w2, w2t);

  // routing chain (split kernels — r17 showed merging serializes and loses 40 us)
  router_k<<<NROUTERBLK, 256, 0, stream>>>(x, rw, eidx, gatesA, bps);
  count_k<<<32, 256, 0, stream>>>(eidx, cc);
  scan_k<<<1, 256, 0, stream>>>(cc, bps, cb, counts, rowsN, out + (size_t)TDIM * DDIM);
  pos_k<<<32, 256, 0, stream>>>(eidx, gatesA, cb, posa, wslotA);
  scatter2_k<<<TDIM, 64, 0, stream>>>(x, eidx, posa, buf);

  // expert GEMM 1: (E,CAP,D) x (E,D,H) -> GELU -> (E,CAP,H)
  // banded grid: wg = e + 8*(ntl + 16*(mt + 16*nth)); NTH=16 (B half-set = 4MB = XCD L2)
  gemm128s<DDIM, DDIM, HDIM, 1, 16, 1, 16><<<4096, 256, 0, stream>>>(
      buf, w1t, b1, hbuf, 0, rowsN);

  // expert GEMM 2, split-K=2 in ONE dispatch; B set already L2-fits
  gemm128s<HDIM / 2, HDIM, DDIM, 0, 8, 2, 16><<<2048, 256, 0, stream>>>(
      hbuf, w2t, b2, outeA, PSTRIDE, rowsN);

  // combine
  combine_k<<<TDIM, 256, 0, stream>>>(outeA, outeA + PSTRIDE, eidx, posa, wslotA, out);
}